// Round 14
// baseline (112.026 us; speedup 1.0000x reference)
//
#include <hip/hip_runtime.h>
#include <math.h>

#define NN 4096
#define DIM 256
#define NHEADS 4
#define HDIM 64

typedef short bf16x8  __attribute__((ext_vector_type(8)));
typedef float f32x4   __attribute__((ext_vector_type(4)));
typedef float f32x16  __attribute__((ext_vector_type(16)));

__device__ __forceinline__ unsigned short f2bf(float f) {
    unsigned int u = __float_as_uint(f);
    u += 0x7fffu + ((u >> 16) & 1u);          // RNE
    return (unsigned short)(u >> 16);
}
__device__ __forceinline__ float bf2f(unsigned short h) {
    return __uint_as_float(((unsigned int)h) << 16);
}
// async global->LDS, 16B per lane, LDS dest = wave-uniform base + lane*16
__device__ __forceinline__ void async16(const void* g, void* l) {
    __builtin_amdgcn_global_load_lds(
        (const __attribute__((address_space(1))) unsigned int*)g,
        (__attribute__((address_space(3))) unsigned int*)l, 16, 0, 0);
}

// ---------------------------------------------------------------------------
// prep: W [256][256] f32 -> WT [256][256] bf16 transposed; 64 blocks
// ---------------------------------------------------------------------------
__global__ __launch_bounds__(256)
void prep_kernel(const float* __restrict__ W0, const float* __restrict__ W1,
                 const float* __restrict__ W2, const float* __restrict__ W3,
                 unsigned short* __restrict__ T0, unsigned short* __restrict__ T1,
                 unsigned short* __restrict__ T2, unsigned short* __restrict__ T3)
{
    __shared__ unsigned short Ts[64][65];
    const int b = blockIdx.x, t = threadIdx.x;
    const int mat = b >> 4, tile = b & 15;
    const int r0 = (tile >> 2) * 64, c0 = (tile & 3) * 64;
    const float* W = (mat == 0) ? W0 : (mat == 1) ? W1 : (mat == 2) ? W2 : W3;
    unsigned short* T = (mat == 0) ? T0 : (mat == 1) ? T1 : (mat == 2) ? T2 : T3;
    {
        int r = t >> 2, c4 = (t & 3) * 16;
        #pragma unroll
        for (int j = 0; j < 4; ++j) {
            float4 v = *reinterpret_cast<const float4*>(W + (size_t)(r0 + r) * DIM + c0 + c4 + j * 4);
            Ts[c4 + j * 4 + 0][r] = f2bf(v.x);
            Ts[c4 + j * 4 + 1][r] = f2bf(v.y);
            Ts[c4 + j * 4 + 2][r] = f2bf(v.z);
            Ts[c4 + j * 4 + 3][r] = f2bf(v.w);
        }
    }
    __syncthreads();
    {
        int d = t >> 2, k4 = (t & 3) * 16;
        #pragma unroll
        for (int j = 0; j < 4; ++j) {
            ushort4 u;
            u.x = Ts[d][k4 + j * 4 + 0];
            u.y = Ts[d][k4 + j * 4 + 1];
            u.z = Ts[d][k4 + j * 4 + 2];
            u.w = Ts[d][k4 + j * 4 + 3];
            *reinterpret_cast<ushort4*>(T + (size_t)(c0 + d) * DIM + r0 + k4 + j * 4) = u;
        }
    }
}

// ---------------------------------------------------------------------------
// qkv_mask: blocks [0,384) = QKV projections; blocks [384,2432) = adj->bitmask.
// mask NATURAL: word[row*64 + wi], bit j = adj[row][wi*64 + j]
// K PRE-SCALED by log2(e)/8. V stored as VT [d][kv], NATURAL kv order.
// ---------------------------------------------------------------------------
__global__ __launch_bounds__(256)
void qkv_mask(const float* __restrict__ x,
              const unsigned short* __restrict__ WqT, const unsigned short* __restrict__ WkT,
              const unsigned short* __restrict__ WvT,
              const float* __restrict__ bq, const float* __restrict__ bk, const float* __restrict__ bv,
              unsigned short* __restrict__ Qo, unsigned short* __restrict__ Ko,
              unsigned short* __restrict__ VTo,
              const int* __restrict__ adj, unsigned long long* __restrict__ maskT)
{
    const int b = blockIdx.x, t = threadIdx.x, w = t >> 6, l = t & 63;

    if (b >= 384) {
        const int ww = (b - 384) * 4 + w;
        for (int idx = ww; idx < 65536; idx += 8192) {   // idx = row*16 + stripe
            const int row = idx >> 4, st = idx & 15;
            const int* ap = adj + (size_t)row * NN + st * 256 + l;
            const int a0 = ap[0];
            const int a1 = ap[64];
            const int a2 = ap[128];
            const int a3 = ap[192];
            unsigned long long b0 = __ballot(a0 != 0);
            unsigned long long b1 = __ballot(a1 != 0);
            unsigned long long b2 = __ballot(a2 != 0);
            unsigned long long b3 = __ballot(a3 != 0);
            if (l < 4) {
                unsigned long long bb = (l == 0) ? b0 : (l == 1) ? b1 : (l == 2) ? b2 : b3;
                maskT[(size_t)row * 64 + st * 4 + l] = bb;
            }
        }
        return;
    }

    const int l15 = l & 15, lg = l >> 4;
    const int which = b >> 7, xb = b & 127;
    const int row0 = xb * 32 + (w >> 1) * 16;
    const int col0 = (w & 1) * 128;
    const unsigned short* WT; const float* bias;
    if (which == 0)      { WT = WqT; bias = bq; }
    else if (which == 1) { WT = WkT; bias = bk; }
    else                 { WT = WvT; bias = bv; }

    f32x4 acc[8] = {};
    for (int k0 = 0; k0 < DIM; k0 += 32) {
        const float* xp = x + (size_t)(row0 + l15) * DIM + k0 + lg * 8;
        float4 x0 = *reinterpret_cast<const float4*>(xp);
        float4 x1 = *reinterpret_cast<const float4*>(xp + 4);
        union { unsigned u[4]; bf16x8 v; } xa;
        asm("v_cvt_pk_bf16_f32 %0, %1, %2" : "=v"(xa.u[0]) : "v"(x0.x), "v"(x0.y));
        asm("v_cvt_pk_bf16_f32 %0, %1, %2" : "=v"(xa.u[1]) : "v"(x0.z), "v"(x0.w));
        asm("v_cvt_pk_bf16_f32 %0, %1, %2" : "=v"(xa.u[2]) : "v"(x1.x), "v"(x1.y));
        asm("v_cvt_pk_bf16_f32 %0, %1, %2" : "=v"(xa.u[3]) : "v"(x1.z), "v"(x1.w));
        #pragma unroll
        for (int nt = 0; nt < 8; ++nt) {
            bf16x8 wb = *(const bf16x8*)(WT + (size_t)(col0 + nt * 16 + l15) * DIM + k0 + lg * 8);
            acc[nt] = __builtin_amdgcn_mfma_f32_16x16x32_bf16(xa.v, wb, acc[nt], 0, 0, 0);
        }
    }
    #pragma unroll
    for (int nt = 0; nt < 8; ++nt) {
        int col = col0 + nt * 16 + l15;
        float bb = bias[col];
        #pragma unroll
        for (int r = 0; r < 4; ++r) {
            int row = row0 + lg * 4 + r;
            float ov = acc[nt][r] + bb;
            if (which == 1) ov *= 0.18033688f;   // log2(e)/8 folded into K
            unsigned short val = f2bf(ov);
            if (which == 2)      VTo[(size_t)col * NN + row] = val;   // natural
            else if (which == 0) Qo[(size_t)row * DIM + col] = val;
            else                 Ko[(size_t)row * DIM + col] = val;
        }
    }
}

// ---------------------------------------------------------------------------
// 32x32-MFMA flash attention. Block = 128 q; 4 waves x 32 q. Per wave-tile
// (32q x 64kv): 16 ds_read_b128 (half the per-q LDS reads of the 16x16
// structure), 16 mfma_32x32x16. Swapped QK^T (A=K, B=Q): S^T col = q =
// lane&31 -> softmax lane-local; PV A-frag assembled via cvt_pk pairs +
// 2 shfl_xor(32) per 16-kv slice (lane<->lane+32 exchange). V natural in
// VT; B-frag = contiguous VT row segment. K pre-scaled -> p = exp2(score).
// K/V double-buffered 32KB LDS, XOR-swizzled source, one barrier/tile.
// Grid = 8*qb*slices, slice-major XCD swizzle (bid&7 = slice&7).
// ---------------------------------------------------------------------------
template<int NTILES>
__global__ __launch_bounds__(256, 4)
void attn_mfma(const unsigned short* __restrict__ Qb, const unsigned short* __restrict__ Kb,
               const unsigned short* __restrict__ VT, const unsigned long long* __restrict__ maskT,
               unsigned short* __restrict__ Opart, float* __restrict__ lpart)
{
    constexpr int NSTR = NTILES / 4;
    __shared__ unsigned short Kt[2][64][64];   // [buf][kv][d]
    __shared__ unsigned short Vt[2][64][64];   // [buf][d][kv]

    const int t = threadIdx.x, w = t >> 6, l = t & 63, l31 = l & 31, hi = l >> 5;
    const int bid = blockIdx.x;
    const int slice = (bid & 7) + 8 * (bid >> 8);
    const int qb    = (bid >> 3) & 31;
    const int h  = slice & 3;
    const int sp = slice >> 2;
    const int kv_base = sp * NTILES * 64;
    const int qbase = qb * 128 + w * 32;
    const int q = qbase + l31;

    // Q B-frags: col=q=lane&31, k = s*16 + hi*8 + e
    bf16x8 qf0, qf1, qf2, qf3;
    {
        const unsigned short* qp = Qb + (size_t)q * DIM + h * HDIM + hi * 8;
        qf0 = *(const bf16x8*)(qp);
        qf1 = *(const bf16x8*)(qp + 16);
        qf2 = *(const bf16x8*)(qp + 32);
        qf3 = *(const bf16x8*)(qp + 48);
    }

    const unsigned long long* mbase = maskT + (size_t)q * 64 + (kv_base >> 6);

    // staging (identical skeleton to the proven kernel)
    const int srow  = w * 16 + (l >> 3);
    const int sunit = (l & 7) ^ (srow & 7);
    const unsigned short* kS = Kb + (size_t)(kv_base + srow) * DIM + h * HDIM + sunit * 8;
    const unsigned short* vS = VT + (size_t)(h * HDIM + srow) * NN + kv_base + sunit * 8;

    // LDS read offsets: global 16B-unit g=(2s+hi), phys = g ^ (row&7); row&7 = l31&7
    const int x7 = l31 & 7;
    const int ko0 = ((0 + hi) ^ x7) << 4;
    const int ko1 = ((2 + hi) ^ x7) << 4;
    const int ko2 = ((4 + hi) ^ x7) << 4;
    const int ko3 = ((6 + hi) ^ x7) << 4;

    f32x16 oacc0 = {}, oacc1 = {};
    float lsum = 0.f;

    {   // prologue: stage tile 0 -> buf 0
        unsigned short* kd = &Kt[0][w * 16][0];
        unsigned short* vd = &Vt[0][w * 16][0];
        async16(kS, kd); async16(kS + 8 * DIM, kd + 8 * 64);
        async16(vS, vd); async16(vS + 8 * NN,  vd + 8 * 64);
    }

    #pragma unroll 1
    for (int st = 0; st < NSTR; ++st) {
        const ulonglong4 m4 = *reinterpret_cast<const ulonglong4*>(mbase + st * 4);

        #pragma unroll
        for (int m = 0; m < 4; ++m) {
            const int tl = st * 4 + m;
            asm volatile("s_waitcnt vmcnt(0)" ::: "memory");
            __builtin_amdgcn_s_barrier();
            __builtin_amdgcn_sched_barrier(0);

            if (tl + 1 < NTILES) {
                const int bb = (tl + 1) & 1;
                unsigned short* kd = &Kt[bb][w * 16][0];
                unsigned short* vd = &Vt[bb][w * 16][0];
                const unsigned short* ks = kS + (size_t)(tl + 1) * 64 * DIM;
                const unsigned short* vs = vS + (tl + 1) * 64;
                async16(ks, kd); async16(ks + 8 * DIM, kd + 8 * 64);
                async16(vs, vd); async16(vs + 8 * NN,  vd + 8 * 64);
            }

            const int cb = tl & 1;
            const char* kbase = (const char*)&Kt[cb][0][0] + l31 * 128;
            const char* vbase = (const char*)&Vt[cb][0][0] + l31 * 128;

            // QK^T swapped: sacc{0,1}[r] = S^T[kv=(r&3)+8(r>>2)+4hi+32*half][q=l31]
            f32x16 sacc0 = {}, sacc1 = {};
            __builtin_amdgcn_s_setprio(1);
            {
                bf16x8 a0 = *(const bf16x8*)(kbase + ko0);
                bf16x8 b0 = *(const bf16x8*)(kbase + 4096 + ko0);
                sacc0 = __builtin_amdgcn_mfma_f32_32x32x16_bf16(a0, qf0, sacc0, 0, 0, 0);
                sacc1 = __builtin_amdgcn_mfma_f32_32x32x16_bf16(b0, qf0, sacc1, 0, 0, 0);
                bf16x8 a1 = *(const bf16x8*)(kbase + ko1);
                bf16x8 b1 = *(const bf16x8*)(kbase + 4096 + ko1);
                sacc0 = __builtin_amdgcn_mfma_f32_32x32x16_bf16(a1, qf1, sacc0, 0, 0, 0);
                sacc1 = __builtin_amdgcn_mfma_f32_32x32x16_bf16(b1, qf1, sacc1, 0, 0, 0);
                bf16x8 a2 = *(const bf16x8*)(kbase + ko2);
                bf16x8 b2 = *(const bf16x8*)(kbase + 4096 + ko2);
                sacc0 = __builtin_amdgcn_mfma_f32_32x32x16_bf16(a2, qf2, sacc0, 0, 0, 0);
                sacc1 = __builtin_amdgcn_mfma_f32_32x32x16_bf16(b2, qf2, sacc1, 0, 0, 0);
                bf16x8 a3 = *(const bf16x8*)(kbase + ko3);
                bf16x8 b3 = *(const bf16x8*)(kbase + 4096 + ko3);
                sacc0 = __builtin_amdgcn_mfma_f32_32x32x16_bf16(a3, qf3, sacc0, 0, 0, 0);
                sacc1 = __builtin_amdgcn_mfma_f32_32x32x16_bf16(b3, qf3, sacc1, 0, 0, 0);
            }
            __builtin_amdgcn_s_setprio(0);

            const unsigned long long w64 =
                (m == 0) ? m4.x : (m == 1) ? m4.y : (m == 2) ? m4.z : m4.w;
            const unsigned long long sh = w64 >> (hi * 4);
            const unsigned bits01 = (unsigned)sh;          // half 0 (kv 0..31)
            const unsigned bits23 = (unsigned)(sh >> 32);  // half 1 (kv 32..63)

            // per half: masked exp2, lsum, pack, exchange, PV
            #pragma unroll
            for (int half = 0; half < 2; ++half) {
                const unsigned bits = half ? bits23 : bits01;
                float p[16];
                #pragma unroll
                for (int r = 0; r < 16; ++r) {
                    const int pos = (r & 3) + 8 * (r >> 2);
                    const unsigned bit = (bits >> pos) & 1u;
                    const float sv = half ? sacc1[r] : sacc0[r];
                    p[r] = exp2f(bit ? sv : -INFINITY);
                }
                lsum += (((p[0] + p[1]) + (p[2] + p[3])) + ((p[4] + p[5]) + (p[6] + p[7]))) +
                        (((p[8] + p[9]) + (p[10] + p[11])) + ((p[12] + p[13]) + (p[14] + p[15])));

                #pragma unroll
                for (int sl = 0; sl < 2; ++sl) {
                    const int rb = sl * 8;
                    const int ko = half ? (sl ? ko3 : ko2) : (sl ? ko1 : ko0);
                    unsigned pk01, pk23, pk45, pk67;
                    asm("v_cvt_pk_bf16_f32 %0, %1, %2" : "=v"(pk01) : "v"(p[rb + 0]), "v"(p[rb + 1]));
                    asm("v_cvt_pk_bf16_f32 %0, %1, %2" : "=v"(pk23) : "v"(p[rb + 2]), "v"(p[rb + 3]));
                    asm("v_cvt_pk_bf16_f32 %0, %1, %2" : "=v"(pk45) : "v"(p[rb + 4]), "v"(p[rb + 5]));
                    asm("v_cvt_pk_bf16_f32 %0, %1, %2" : "=v"(pk67) : "v"(p[rb + 6]), "v"(p[rb + 7]));
                    // exchange across lane<->lane+32: hi=0 sends pk45/pk67 (kv +8..11),
                    // hi=1 sends pk01/pk23 (kv +4..7)
                    const unsigned send0 = hi ? pk01 : pk45;
                    const unsigned send1 = hi ? pk23 : pk67;
                    const unsigned recv0 = (unsigned)__shfl_xor((int)send0, 32);
                    const unsigned recv1 = (unsigned)__shfl_xor((int)send1, 32);
                    union { unsigned u[4]; bf16x8 v; } pa;
                    pa.u[0] = hi ? recv0 : pk01;
                    pa.u[1] = hi ? recv1 : pk23;
                    pa.u[2] = hi ? pk45 : recv0;
                    pa.u[3] = hi ? pk67 : recv1;

                    bf16x8 vb0 = *(const bf16x8*)(vbase + ko);          // d = l31
                    bf16x8 vb1 = *(const bf16x8*)(vbase + 4096 + ko);   // d = l31+32
                    __builtin_amdgcn_s_setprio(1);
                    oacc0 = __builtin_amdgcn_mfma_f32_32x32x16_bf16(pa.v, vb0, oacc0, 0, 0, 0);
                    oacc1 = __builtin_amdgcn_mfma_f32_32x32x16_bf16(pa.v, vb1, oacc1, 0, 0, 0);
                    __builtin_amdgcn_s_setprio(0);
                }
            }
            __builtin_amdgcn_sched_barrier(0);
            // no exit barrier: next tile's entry barrier + buffer parity protect
        }
    }

    // row sum: own 32 kv + partner's 32 kv
    lsum += __shfl_xor(lsum, 32);
    if (hi == 0)
        lpart[((size_t)sp * NN + q) * NHEADS + h] = lsum;

    #pragma unroll
    for (int r = 0; r < 16; ++r) {
        const int qr = qbase + (r & 3) + 8 * (r >> 2) + 4 * hi;
        Opart[((size_t)sp * NN + qr) * DIM + h * HDIM + l31]      = f2bf(oacc0[r]);
        Opart[((size_t)sp * NN + qr) * DIM + h * HDIM + 32 + l31] = f2bf(oacc1[r]);
    }
}

// ---------------------------------------------------------------------------
// out_ln_fused: combine kv-splits (normalize) into LDS, then output
// projection + bias + residual + LayerNorm. 256 blocks x 16 rows.
// ---------------------------------------------------------------------------
__global__ __launch_bounds__(256)
void out_ln_fused(const unsigned short* __restrict__ Opart, const float* __restrict__ lpart,
                  const unsigned short* __restrict__ WoT, const float* __restrict__ bo,
                  const unsigned short* __restrict__ Rb, const float* __restrict__ gamma,
                  const float* __restrict__ beta, float* __restrict__ out, int S)
{
    __shared__ unsigned short As[16][264];
    __shared__ float redsum[4][16];
    __shared__ float redsq[4][16];
    const int t = threadIdx.x, w = t >> 6, l = t & 63, l15 = l & 15, lg = l >> 4;
    const int row0 = blockIdx.x * 16;

    {   // combine
        const int row = t >> 4;
        const int d0  = (t & 15) * 16;
        const int hh  = d0 >> 6;
        float lsum = 0.f;
        for (int s = 0; s < S; ++s)
            lsum += lpart[((size_t)s * NN + row0 + row) * NHEADS + hh];
        const float inv = 1.f / lsum;
        float a16[16] = {};
        for (int s = 0; s < S; ++s) {
            const unsigned short* op = Opart + ((size_t)s * NN + row0 + row) * DIM + d0;
            #pragma unroll
            for (int j4 = 0; j4 < 4; ++j4) {
                ushort4 u = *reinterpret_cast<const ushort4*>(op + j4 * 4);
                a16[j4 * 4 + 0] += bf2f(u.x);
                a16[j4 * 4 + 1] += bf2f(u.y);
                a16[j4 * 4 + 2] += bf2f(u.z);
                a16[j4 * 4 + 3] += bf2f(u.w);
            }
        }
        #pragma unroll
        for (int j4 = 0; j4 < 4; ++j4) {
            ushort4 ov;
            ov.x = f2bf(a16[j4 * 4 + 0] * inv);
            ov.y = f2bf(a16[j4 * 4 + 1] * inv);
            ov.z = f2bf(a16[j4 * 4 + 2] * inv);
            ov.w = f2bf(a16[j4 * 4 + 3] * inv);
            *reinterpret_cast<ushort4*>(&As[row][d0 + j4 * 4]) = ov;
        }
    }
    __syncthreads();

    const int col0 = w * 64;
    f32x4 acc[4] = {};
    for (int k0 = 0; k0 < DIM; k0 += 32) {
        bf16x8 xa = *reinterpret_cast<const bf16x8*>(&As[l15][k0 + lg * 8]);
        #pragma unroll
        for (int nt = 0; nt < 4; ++nt) {
            bf16x8 wb = *(const bf16x8*)(WoT + (size_t)(col0 + nt * 16 + l15) * DIM + k0 + lg * 8);
            acc[nt] = __builtin_amdgcn_mfma_f32_16x16x32_bf16(xa, wb, acc[nt], 0, 0, 0);
        }
    }

    float psum[4] = {0, 0, 0, 0}, psq[4] = {0, 0, 0, 0};
    #pragma unroll
    for (int nt = 0; nt < 4; ++nt) {
        int col = col0 + nt * 16 + l15;
        float bb = bo[col];
        #pragma unroll
        for (int r = 0; r < 4; ++r) {
            int row = row0 + lg * 4 + r;
            float xv = acc[nt][r] + bb + bf2f(Rb[(size_t)row * DIM + col]);
            acc[nt][r] = xv;
            psum[r] += xv; psq[r] += xv * xv;
        }
    }
    #pragma unroll
    for (int r = 0; r < 4; ++r) {
        float s = psum[r], qq = psq[r];
        s += __shfl_xor(s, 1); qq += __shfl_xor(qq, 1);
        s += __shfl_xor(s, 2); qq += __shfl_xor(qq, 2);
        s += __shfl_xor(s, 4); qq += __shfl_xor(qq, 4);
        s += __shfl_xor(s, 8); qq += __shfl_xor(qq, 8);
        psum[r] = s; psq[r] = qq;
    }
    if (l15 == 0) {
        #pragma unroll
        for (int r = 0; r < 4; ++r) {
            redsum[w][lg * 4 + r] = psum[r];
            redsq[w][lg * 4 + r]  = psq[r];
        }
    }
    __syncthreads();

    float msave[4], rsave[4];
    #pragma unroll
    for (int r = 0; r < 4; ++r) {
        int row = lg * 4 + r;
        float s = redsum[0][row] + redsum[1][row] + redsum[2][row] + redsum[3][row];
        float qq = redsq[0][row] + redsq[1][row] + redsq[2][row] + redsq[3][row];
        float mean = s * (1.f / 256.f);
        float var  = qq * (1.f / 256.f) - mean * mean;
        msave[r] = mean;
        rsave[r] = rsqrtf(var + 1e-5f);
    }
    #pragma unroll
    for (int nt = 0; nt < 4; ++nt) {
        int col = col0 + nt * 16 + l15;
        float g = gamma[col], bt = beta[col];
        #pragma unroll
        for (int r = 0; r < 4; ++r) {
            int row = row0 + lg * 4 + r;
            out[(size_t)row * DIM + col] = (acc[nt][r] - msave[r]) * rsave[r] * g + bt;
        }
    }
}

// ---------------------------------------------------------------------------
extern "C" void kernel_launch(void* const* d_in, const int* in_sizes, int n_in,
                              void* d_out, int out_size, void* d_ws, size_t ws_size,
                              hipStream_t stream) {
    const float* x     = (const float*)d_in[0];
    const int*   adj   = (const int*)  d_in[1];
    const float* Wq    = (const float*)d_in[2];
    const float* bq    = (const float*)d_in[3];
    const float* Wk    = (const float*)d_in[4];
    const float* bk    = (const float*)d_in[5];
    const float* Wv    = (const float*)d_in[6];
    const float* bv    = (const float*)d_in[7];
    const float* Wo    = (const float*)d_in[8];
    const float* bo    = (const float*)d_in[9];
    const float* gamma = (const float*)d_in[10];
    const float* beta  = (const float*)d_in[11];
    float* out = (float*)d_out;

    char* ws = (char*)d_ws;
    const size_t MB = 1u << 20;
    unsigned short*     Qb    = (unsigned short*)(ws + 0 * MB);        // 2 MB
    unsigned short*     Kb    = (unsigned short*)(ws + 2 * MB);        // 2 MB
    unsigned short*     VT    = (unsigned short*)(ws + 4 * MB);        // 2 MB
    unsigned long long* maskT = (unsigned long long*)(ws + 6 * MB);    // 2 MB
    unsigned short*     WqT   = (unsigned short*)(ws + 8 * MB);        // 4 x 128 KB
    unsigned short*     WkT   = (unsigned short*)(ws + 8 * MB + 128 * 1024);
    unsigned short*     WvT   = (unsigned short*)(ws + 8 * MB + 256 * 1024);
    unsigned short*     WoT   = (unsigned short*)(ws + 8 * MB + 384 * 1024);
    float*              lpart = (float*)(ws + 10 * MB + 512 * 1024);   // 512 KB
    unsigned short*     Opart = (unsigned short*)(ws + 11 * MB);       // 16 MB (S=8)

    const int S = (ws_size >= 27 * MB) ? 8 : 4;

    prep_kernel<<<64, 256, 0, stream>>>(Wq, Wk, Wv, Wo, WqT, WkT, WvT, WoT);

    qkv_mask<<<384 + 2048, 256, 0, stream>>>(
        x, WqT, WkT, WvT, bq, bk, bv, Qb, Kb, VT, adj, maskT);

    if (S == 8)
        attn_mfma<8><<<1024, 256, 0, stream>>>(Qb, Kb, VT, maskT, Opart, lpart);
    else
        attn_mfma<16><<<512, 256, 0, stream>>>(Qb, Kb, VT, maskT, Opart, lpart);

    out_ln_fused<<<NN / 16, 256, 0, stream>>>(
        Opart, lpart, WoT, bo, Qb, gamma, beta, out, S);
}

// Round 15
// 85.056 us; speedup vs baseline: 1.3171x; 1.3171x over previous
//
#include <hip/hip_runtime.h>
#include <math.h>

#define NN 4096
#define DIM 256
#define NHEADS 4
#define HDIM 64

typedef short bf16x8 __attribute__((ext_vector_type(8)));
typedef float f32x4  __attribute__((ext_vector_type(4)));

__device__ __forceinline__ unsigned short f2bf(float f) {
    unsigned int u = __float_as_uint(f);
    u += 0x7fffu + ((u >> 16) & 1u);          // RNE
    return (unsigned short)(u >> 16);
}
__device__ __forceinline__ float bf2f(unsigned short h) {
    return __uint_as_float(((unsigned int)h) << 16);
}
// async global->LDS, 16B per lane, LDS dest = wave-uniform base + lane*16
__device__ __forceinline__ void async16(const void* g, void* l) {
    __builtin_amdgcn_global_load_lds(
        (const __attribute__((address_space(1))) unsigned int*)g,
        (__attribute__((address_space(3))) unsigned int*)l, 16, 0, 0);
}

// ---------------------------------------------------------------------------
// prep: W [256][256] f32 -> WT [256][256] bf16 transposed; 64 blocks
// ---------------------------------------------------------------------------
__global__ __launch_bounds__(256)
void prep_kernel(const float* __restrict__ W0, const float* __restrict__ W1,
                 const float* __restrict__ W2, const float* __restrict__ W3,
                 unsigned short* __restrict__ T0, unsigned short* __restrict__ T1,
                 unsigned short* __restrict__ T2, unsigned short* __restrict__ T3)
{
    __shared__ unsigned short Ts[64][65];
    const int b = blockIdx.x, t = threadIdx.x;
    const int mat = b >> 4, tile = b & 15;
    const int r0 = (tile >> 2) * 64, c0 = (tile & 3) * 64;
    const float* W = (mat == 0) ? W0 : (mat == 1) ? W1 : (mat == 2) ? W2 : W3;
    unsigned short* T = (mat == 0) ? T0 : (mat == 1) ? T1 : (mat == 2) ? T2 : T3;
    {
        int r = t >> 2, c4 = (t & 3) * 16;
        #pragma unroll
        for (int j = 0; j < 4; ++j) {
            float4 v = *reinterpret_cast<const float4*>(W + (size_t)(r0 + r) * DIM + c0 + c4 + j * 4);
            Ts[c4 + j * 4 + 0][r] = f2bf(v.x);
            Ts[c4 + j * 4 + 1][r] = f2bf(v.y);
            Ts[c4 + j * 4 + 2][r] = f2bf(v.z);
            Ts[c4 + j * 4 + 3][r] = f2bf(v.w);
        }
    }
    __syncthreads();
    {
        int d = t >> 2, k4 = (t & 3) * 16;
        #pragma unroll
        for (int j = 0; j < 4; ++j) {
            ushort4 u;
            u.x = Ts[d][k4 + j * 4 + 0];
            u.y = Ts[d][k4 + j * 4 + 1];
            u.z = Ts[d][k4 + j * 4 + 2];
            u.w = Ts[d][k4 + j * 4 + 3];
            *reinterpret_cast<ushort4*>(T + (size_t)(c0 + d) * DIM + r0 + k4 + j * 4) = u;
        }
    }
}

// ---------------------------------------------------------------------------
// qkv_mask: blocks [0,384) = QKV projections (MFMA, f32 x input, inline cvt);
// blocks [384,2432) = adj -> bitmask.
// mask layout NATURAL: word[row*64 + wi], bit j = adj[row][wi*64 + j]
// K stored PRE-SCALED by log2(e)/8 so attn's p = exp2(score) directly.
// V token rows permuted within each 64-block: kv -> pos =
//   ((nt&1)<<5)|(lg<<3)|((nt>>1)<<2)|r  (aligns V rows with lane-local P).
// ---------------------------------------------------------------------------
__global__ __launch_bounds__(256)
void qkv_mask(const float* __restrict__ x,
              const unsigned short* __restrict__ WqT, const unsigned short* __restrict__ WkT,
              const unsigned short* __restrict__ WvT,
              const float* __restrict__ bq, const float* __restrict__ bk, const float* __restrict__ bv,
              unsigned short* __restrict__ Qo, unsigned short* __restrict__ Ko,
              unsigned short* __restrict__ VTo,
              const int* __restrict__ adj, unsigned long long* __restrict__ maskT)
{
    const int b = blockIdx.x, t = threadIdx.x, w = t >> 6, l = t & 63;

    if (b >= 384) {
        const int ww = (b - 384) * 4 + w;
        for (int idx = ww; idx < 65536; idx += 8192) {   // idx = row*16 + stripe
            const int row = idx >> 4, st = idx & 15;
            const int* ap = adj + (size_t)row * NN + st * 256 + l;
            const int a0 = ap[0];
            const int a1 = ap[64];
            const int a2 = ap[128];
            const int a3 = ap[192];
            unsigned long long b0 = __ballot(a0 != 0);
            unsigned long long b1 = __ballot(a1 != 0);
            unsigned long long b2 = __ballot(a2 != 0);
            unsigned long long b3 = __ballot(a3 != 0);
            if (l < 4) {
                unsigned long long bb = (l == 0) ? b0 : (l == 1) ? b1 : (l == 2) ? b2 : b3;
                maskT[(size_t)row * 64 + st * 4 + l] = bb;
            }
        }
        return;
    }

    const int l15 = l & 15, lg = l >> 4;
    const int which = b >> 7, xb = b & 127;
    const int row0 = xb * 32 + (w >> 1) * 16;
    const int col0 = (w & 1) * 128;
    const unsigned short* WT; const float* bias;
    if (which == 0)      { WT = WqT; bias = bq; }
    else if (which == 1) { WT = WkT; bias = bk; }
    else                 { WT = WvT; bias = bv; }

    f32x4 acc[8] = {};
    for (int k0 = 0; k0 < DIM; k0 += 32) {
        const float* xp = x + (size_t)(row0 + l15) * DIM + k0 + lg * 8;
        float4 x0 = *reinterpret_cast<const float4*>(xp);
        float4 x1 = *reinterpret_cast<const float4*>(xp + 4);
        union { unsigned u[4]; bf16x8 v; } xa;
        asm("v_cvt_pk_bf16_f32 %0, %1, %2" : "=v"(xa.u[0]) : "v"(x0.x), "v"(x0.y));
        asm("v_cvt_pk_bf16_f32 %0, %1, %2" : "=v"(xa.u[1]) : "v"(x0.z), "v"(x0.w));
        asm("v_cvt_pk_bf16_f32 %0, %1, %2" : "=v"(xa.u[2]) : "v"(x1.x), "v"(x1.y));
        asm("v_cvt_pk_bf16_f32 %0, %1, %2" : "=v"(xa.u[3]) : "v"(x1.z), "v"(x1.w));
        #pragma unroll
        for (int nt = 0; nt < 8; ++nt) {
            bf16x8 wb = *(const bf16x8*)(WT + (size_t)(col0 + nt * 16 + l15) * DIM + k0 + lg * 8);
            acc[nt] = __builtin_amdgcn_mfma_f32_16x16x32_bf16(xa.v, wb, acc[nt], 0, 0, 0);
        }
    }
    #pragma unroll
    for (int nt = 0; nt < 8; ++nt) {
        int col = col0 + nt * 16 + l15;
        float bb = bias[col];
        #pragma unroll
        for (int r = 0; r < 4; ++r) {
            int row = row0 + lg * 4 + r;
            float ov = acc[nt][r] + bb;
            if (which == 1) ov *= 0.18033688f;   // log2(e)/8 folded into K
            unsigned short val = f2bf(ov);
            if (which == 2) {
                int rb = row & 63;
                int vnt = rb >> 4, vlg = (rb >> 2) & 3, vr = rb & 3;
                int pos = ((vnt & 1) << 5) | (vlg << 3) | ((vnt >> 1) << 2) | vr;
                VTo[(size_t)col * NN + ((row & ~63) | pos)] = val;
            } else if (which == 0) Qo[(size_t)row * DIM + col] = val;
            else                   Ko[(size_t)row * DIM + col] = val;
        }
    }
}

// ---------------------------------------------------------------------------
// MFMA flash attention — proven structure (52 us, VGPR 52, no spill).
// Block = 64 q; 4 thin waves x 16 q; K+V double-buffered 32KB LDS via
// global_load_lds (XOR-swizzled source), depth-1 issue-early prefetch, one
// barrier/tile. Swapped-operand QK^T (P lane-local, q=l15); V pre-permuted
// so PV A-frag is register packing. K pre-scaled -> p = exp2(score). lsum
// via ones-column MFMA. Grid 2048 = 64 qb x 32 slices, slice-major XCD
// swizzle (bid&7 = slice&7): 4 slices/XCD, K/V L2-resident.
// ---------------------------------------------------------------------------
template<int NTILES>
__global__ __launch_bounds__(256, 8)
void attn_mfma(const unsigned short* __restrict__ Qb, const unsigned short* __restrict__ Kb,
               const unsigned short* __restrict__ VT, const unsigned long long* __restrict__ maskT,
               unsigned short* __restrict__ Opart, float* __restrict__ lpart)
{
    constexpr int NSTR = NTILES / 4;
    __shared__ unsigned short Kt[2][64][64];
    __shared__ unsigned short Vt[2][64][64];

    const int t = threadIdx.x, w = t >> 6, l = t & 63, l15 = l & 15, lg = l >> 4;
    const int bid = blockIdx.x;
    // slices = 32; bid = (slice&7) + 8*qb + 8*64*(slice>>3)
    const int slice = (bid & 7) + 8 * (bid >> 9);
    const int qb    = (bid >> 3) & 63;
    const int h  = slice & 3;
    const int sp = slice >> 2;
    const int n0 = qb * 64;
    const int kv_base = sp * NTILES * 64;
    const int qrow = n0 + w * 16;

    const unsigned short* qp = Qb + (size_t)(qrow + l15) * DIM + h * HDIM + lg * 8;
    const bf16x8 qa0 = *(const bf16x8*)(qp);
    const bf16x8 qa1 = *(const bf16x8*)(qp + 32);

    const unsigned long long* mbase = maskT + (size_t)(qrow + l15) * 64 + (kv_base >> 6);

    const int srow  = w * 16 + (l >> 3);
    const int sunit = (l & 7) ^ (srow & 7);
    const unsigned short* kS = Kb + (size_t)(kv_base + srow) * DIM + h * HDIM + sunit * 8;
    const unsigned short* vS = VT + (size_t)(h * HDIM + srow) * NN + kv_base + sunit * 8;

    const int xr  = l15 & 7;
    const int ko0 = (lg ^ xr) << 4;
    const int ko1 = ((4 + lg) ^ xr) << 4;

    const short onev = (l15 == 0) ? (short)0x3F80 : (short)0;  // bf16 1.0, col 0
    const bf16x8 onesb = {onev, onev, onev, onev, onev, onev, onev, onev};

    f32x4 oa[4] = {};
    f32x4 os = {};

    {   // prologue: stage tile 0 -> buf 0
        unsigned short* kd = &Kt[0][w * 16][0];
        unsigned short* vd = &Vt[0][w * 16][0];
        async16(kS, kd); async16(kS + 8 * DIM, kd + 8 * 64);
        async16(vS, vd); async16(vS + 8 * NN,  vd + 8 * 64);
    }

    #pragma unroll 1
    for (int st = 0; st < NSTR; ++st) {
        const ulonglong4 m4 = *reinterpret_cast<const ulonglong4*>(mbase + st * 4);

        #pragma unroll
        for (int m = 0; m < 4; ++m) {
            const int tl = st * 4 + m;
            asm volatile("s_waitcnt vmcnt(0)" ::: "memory");   // this tile landed
            __builtin_amdgcn_s_barrier();
            __builtin_amdgcn_sched_barrier(0);

            if (tl + 1 < NTILES) {   // issue next tile into the other buffer
                const int bb = (tl + 1) & 1;
                unsigned short* kd = &Kt[bb][w * 16][0];
                unsigned short* vd = &Vt[bb][w * 16][0];
                const unsigned short* ks = kS + (size_t)(tl + 1) * 64 * DIM;
                const unsigned short* vs = vS + (tl + 1) * 64;
                async16(ks, kd); async16(ks + 8 * DIM, kd + 8 * 64);
                async16(vs, vd); async16(vs + 8 * NN,  vd + 8 * 64);
            }

            const int cb = tl & 1;
            const char* kbase = (const char*)&Kt[cb][0][0] + l15 * 128;
            const char* vbase = (const char*)&Vt[cb][0][0] + l15 * 128;

            // QK^T swapped: sa[nt][r] = score[q=l15][kv = nt*16 + lg*4 + r]
            f32x4 sa[4] = {};
            __builtin_amdgcn_s_setprio(1);
            #pragma unroll
            for (int nt = 0; nt < 4; ++nt) {
                bf16x8 kb0 = *(const bf16x8*)(kbase + nt * 2048 + ko0);
                bf16x8 kb1 = *(const bf16x8*)(kbase + nt * 2048 + ko1);
                sa[nt] = __builtin_amdgcn_mfma_f32_16x16x32_bf16(kb0, qa0, sa[nt], 0, 0, 0);
                sa[nt] = __builtin_amdgcn_mfma_f32_16x16x32_bf16(kb1, qa1, sa[nt], 0, 0, 0);
            }
            __builtin_amdgcn_s_setprio(0);

            // masked p = exp2(score); natural mask word, lane shift lg*4
            const unsigned long long w64 =
                (m == 0) ? m4.x : (m == 1) ? m4.y : (m == 2) ? m4.z : m4.w;
            const unsigned long long sh = w64 >> (lg * 4);
            const unsigned shlo = (unsigned)sh, shhi = (unsigned)(sh >> 32);
            float p[4][4];
            #pragma unroll
            for (int nt = 0; nt < 4; ++nt) {
                #pragma unroll
                for (int r = 0; r < 4; ++r) {
                    const int bitpos = nt * 16 + r;
                    const unsigned word = (bitpos < 32) ? shlo : shhi;
                    const unsigned bit = (word >> (bitpos & 31)) & 1u;
                    p[nt][r] = exp2f(bit ? sa[nt][r] : -INFINITY);
                }
            }
            union { unsigned u[4]; bf16x8 v; } a0, a1;
            asm("v_cvt_pk_bf16_f32 %0, %1, %2" : "=v"(a0.u[0]) : "v"(p[0][0]), "v"(p[0][1]));
            asm("v_cvt_pk_bf16_f32 %0, %1, %2" : "=v"(a0.u[1]) : "v"(p[0][2]), "v"(p[0][3]));
            asm("v_cvt_pk_bf16_f32 %0, %1, %2" : "=v"(a0.u[2]) : "v"(p[2][0]), "v"(p[2][1]));
            asm("v_cvt_pk_bf16_f32 %0, %1, %2" : "=v"(a0.u[3]) : "v"(p[2][2]), "v"(p[2][3]));
            asm("v_cvt_pk_bf16_f32 %0, %1, %2" : "=v"(a1.u[0]) : "v"(p[1][0]), "v"(p[1][1]));
            asm("v_cvt_pk_bf16_f32 %0, %1, %2" : "=v"(a1.u[1]) : "v"(p[1][2]), "v"(p[1][3]));
            asm("v_cvt_pk_bf16_f32 %0, %1, %2" : "=v"(a1.u[2]) : "v"(p[3][0]), "v"(p[3][1]));
            asm("v_cvt_pk_bf16_f32 %0, %1, %2" : "=v"(a1.u[3]) : "v"(p[3][2]), "v"(p[3][3]));
            const bf16x8 pa0 = a0.v;
            const bf16x8 pa1 = a1.v;

            // PV + row-sum via ones column (V rows already in fragment order)
            __builtin_amdgcn_s_setprio(1);
            #pragma unroll
            for (int nt = 0; nt < 4; ++nt) {
                bf16x8 vb0 = *(const bf16x8*)(vbase + nt * 2048 + ko0);
                bf16x8 vb1 = *(const bf16x8*)(vbase + nt * 2048 + ko1);
                oa[nt] = __builtin_amdgcn_mfma_f32_16x16x32_bf16(pa0, vb0, oa[nt], 0, 0, 0);
                oa[nt] = __builtin_amdgcn_mfma_f32_16x16x32_bf16(pa1, vb1, oa[nt], 0, 0, 0);
            }
            os = __builtin_amdgcn_mfma_f32_16x16x32_bf16(pa0, onesb, os, 0, 0, 0);
            os = __builtin_amdgcn_mfma_f32_16x16x32_bf16(pa1, onesb, os, 0, 0, 0);
            __builtin_amdgcn_s_setprio(0);
            // no exit barrier: next tile's entry barrier + buffer parity protect
        }
    }

    #pragma unroll
    for (int r = 0; r < 4; ++r) {
        const int qr = qrow + lg * 4 + r;
        #pragma unroll
        for (int nt = 0; nt < 4; ++nt)
            Opart[((size_t)sp * NN + qr) * DIM + h * HDIM + nt * 16 + l15] = f2bf(oa[nt][r]);
        if (l15 == 0)
            lpart[((size_t)sp * NN + qr) * NHEADS + h] = os[r];
    }
}

// ---------------------------------------------------------------------------
// out_ln_fused: combine kv-splits (normalize) into LDS, then output
// projection + bias + residual + LayerNorm. 256 blocks x 16 rows.
// ---------------------------------------------------------------------------
__global__ __launch_bounds__(256)
void out_ln_fused(const unsigned short* __restrict__ Opart, const float* __restrict__ lpart,
                  const unsigned short* __restrict__ WoT, const float* __restrict__ bo,
                  const unsigned short* __restrict__ Rb, const float* __restrict__ gamma,
                  const float* __restrict__ beta, float* __restrict__ out, int S)
{
    __shared__ unsigned short As[16][264];
    __shared__ float redsum[4][16];
    __shared__ float redsq[4][16];
    const int t = threadIdx.x, w = t >> 6, l = t & 63, l15 = l & 15, lg = l >> 4;
    const int row0 = blockIdx.x * 16;

    {   // combine: thread -> row = t>>4 (16), d-chunk = (t&15)*16
        const int row = t >> 4;
        const int d0  = (t & 15) * 16;
        const int hh  = d0 >> 6;
        float lsum = 0.f;
        for (int s = 0; s < S; ++s)
            lsum += lpart[((size_t)s * NN + row0 + row) * NHEADS + hh];
        const float inv = 1.f / lsum;
        float a16[16] = {};
        for (int s = 0; s < S; ++s) {
            const unsigned short* op = Opart + ((size_t)s * NN + row0 + row) * DIM + d0;
            #pragma unroll
            for (int j4 = 0; j4 < 4; ++j4) {
                ushort4 u = *reinterpret_cast<const ushort4*>(op + j4 * 4);
                a16[j4 * 4 + 0] += bf2f(u.x);
                a16[j4 * 4 + 1] += bf2f(u.y);
                a16[j4 * 4 + 2] += bf2f(u.z);
                a16[j4 * 4 + 3] += bf2f(u.w);
            }
        }
        #pragma unroll
        for (int j4 = 0; j4 < 4; ++j4) {
            ushort4 ov;
            ov.x = f2bf(a16[j4 * 4 + 0] * inv);
            ov.y = f2bf(a16[j4 * 4 + 1] * inv);
            ov.z = f2bf(a16[j4 * 4 + 2] * inv);
            ov.w = f2bf(a16[j4 * 4 + 3] * inv);
            *reinterpret_cast<ushort4*>(&As[row][d0 + j4 * 4]) = ov;
        }
    }
    __syncthreads();

    const int col0 = w * 64;
    f32x4 acc[4] = {};
    for (int k0 = 0; k0 < DIM; k0 += 32) {
        bf16x8 xa = *reinterpret_cast<const bf16x8*>(&As[l15][k0 + lg * 8]);
        #pragma unroll
        for (int nt = 0; nt < 4; ++nt) {
            bf16x8 wb = *(const bf16x8*)(WoT + (size_t)(col0 + nt * 16 + l15) * DIM + k0 + lg * 8);
            acc[nt] = __builtin_amdgcn_mfma_f32_16x16x32_bf16(xa, wb, acc[nt], 0, 0, 0);
        }
    }

    float psum[4] = {0, 0, 0, 0}, psq[4] = {0, 0, 0, 0};
    #pragma unroll
    for (int nt = 0; nt < 4; ++nt) {
        int col = col0 + nt * 16 + l15;
        float bb = bo[col];
        #pragma unroll
        for (int r = 0; r < 4; ++r) {
            int row = row0 + lg * 4 + r;
            float xv = acc[nt][r] + bb + bf2f(Rb[(size_t)row * DIM + col]);
            acc[nt][r] = xv;
            psum[r] += xv; psq[r] += xv * xv;
        }
    }
    #pragma unroll
    for (int r = 0; r < 4; ++r) {
        float s = psum[r], q = psq[r];
        s += __shfl_xor(s, 1); q += __shfl_xor(q, 1);
        s += __shfl_xor(s, 2); q += __shfl_xor(q, 2);
        s += __shfl_xor(s, 4); q += __shfl_xor(q, 4);
        s += __shfl_xor(s, 8); q += __shfl_xor(q, 8);
        psum[r] = s; psq[r] = q;
    }
    if (l15 == 0) {
        #pragma unroll
        for (int r = 0; r < 4; ++r) {
            redsum[w][lg * 4 + r] = psum[r];
            redsq[w][lg * 4 + r]  = psq[r];
        }
    }
    __syncthreads();

    float msave[4], rsave[4];
    #pragma unroll
    for (int r = 0; r < 4; ++r) {
        int row = lg * 4 + r;
        float s = redsum[0][row] + redsum[1][row] + redsum[2][row] + redsum[3][row];
        float q = redsq[0][row] + redsq[1][row] + redsq[2][row] + redsq[3][row];
        float mean = s * (1.f / 256.f);
        float var  = q * (1.f / 256.f) - mean * mean;
        msave[r] = mean;
        rsave[r] = rsqrtf(var + 1e-5f);
    }
    #pragma unroll
    for (int nt = 0; nt < 4; ++nt) {
        int col = col0 + nt * 16 + l15;
        float g = gamma[col], bt = beta[col];
        #pragma unroll
        for (int r = 0; r < 4; ++r) {
            int row = row0 + lg * 4 + r;
            out[(size_t)row * DIM + col] = (acc[nt][r] - msave[r]) * rsave[r] * g + bt;
        }
    }
}

// ---------------------------------------------------------------------------
extern "C" void kernel_launch(void* const* d_in, const int* in_sizes, int n_in,
                              void* d_out, int out_size, void* d_ws, size_t ws_size,
                              hipStream_t stream) {
    const float* x     = (const float*)d_in[0];
    const int*   adj   = (const int*)  d_in[1];
    const float* Wq    = (const float*)d_in[2];
    const float* bq    = (const float*)d_in[3];
    const float* Wk    = (const float*)d_in[4];
    const float* bk    = (const float*)d_in[5];
    const float* Wv    = (const float*)d_in[6];
    const float* bv    = (const float*)d_in[7];
    const float* Wo    = (const float*)d_in[8];
    const float* bo    = (const float*)d_in[9];
    const float* gamma = (const float*)d_in[10];
    const float* beta  = (const float*)d_in[11];
    float* out = (float*)d_out;

    char* ws = (char*)d_ws;
    const size_t MB = 1u << 20;
    unsigned short*     Qb    = (unsigned short*)(ws + 0 * MB);        // 2 MB
    unsigned short*     Kb    = (unsigned short*)(ws + 2 * MB);        // 2 MB
    unsigned short*     VT    = (unsigned short*)(ws + 4 * MB);        // 2 MB
    unsigned long long* maskT = (unsigned long long*)(ws + 6 * MB);    // 2 MB
    unsigned short*     WqT   = (unsigned short*)(ws + 8 * MB);        // 4 x 128 KB
    unsigned short*     WkT   = (unsigned short*)(ws + 8 * MB + 128 * 1024);
    unsigned short*     WvT   = (unsigned short*)(ws + 8 * MB + 256 * 1024);
    unsigned short*     WoT   = (unsigned short*)(ws + 8 * MB + 384 * 1024);
    float*              lpart = (float*)(ws + 10 * MB + 512 * 1024);   // 512 KB
    unsigned short*     Opart = (unsigned short*)(ws + 11 * MB);       // 16 MB (S=8)

    const int S = (ws_size >= 27 * MB) ? 8 : 4;

    prep_kernel<<<64, 256, 0, stream>>>(Wq, Wk, Wv, Wo, WqT, WkT, WvT, WoT);

    qkv_mask<<<384 + 2048, 256, 0, stream>>>(
        x, WqT, WkT, WvT, bq, bk, bv, Qb, Kb, VT, adj, maskT);

    if (S == 8)
        attn_mfma<8><<<2048, 256, 0, stream>>>(Qb, Kb, VT, maskT, Opart, lpart);
    else
        attn_mfma<16><<<1024, 256, 0, stream>>>(Qb, Kb, VT, maskT, Opart, lpart);

    out_ln_fused<<<NN / 16, 256, 0, stream>>>(
        Opart, lpart, WoT, bo, Qb, gamma, beta, out, S);
}

// Round 16
// 84.238 us; speedup vs baseline: 1.3299x; 1.0097x over previous
//
#include <hip/hip_runtime.h>
#include <math.h>

#define NN 4096
#define DIM 256
#define NHEADS 4
#define HDIM 64

typedef short bf16x8 __attribute__((ext_vector_type(8)));
typedef float f32x4  __attribute__((ext_vector_type(4)));

__device__ __forceinline__ unsigned short f2bf(float f) {
    unsigned int u = __float_as_uint(f);
    u += 0x7fffu + ((u >> 16) & 1u);          // RNE
    return (unsigned short)(u >> 16);
}
__device__ __forceinline__ float bf2f(unsigned short h) {
    return __uint_as_float(((unsigned int)h) << 16);
}
// async global->LDS, 16B per lane, LDS dest = wave-uniform base + lane*16
__device__ __forceinline__ void async16(const void* g, void* l) {
    __builtin_amdgcn_global_load_lds(
        (const __attribute__((address_space(1))) unsigned int*)g,
        (__attribute__((address_space(3))) unsigned int*)l, 16, 0, 0);
}

// ---------------------------------------------------------------------------
// prep: W [256][256] f32 -> WT [256][256] bf16 transposed; 64 blocks
// ---------------------------------------------------------------------------
__global__ __launch_bounds__(256)
void prep_kernel(const float* __restrict__ W0, const float* __restrict__ W1,
                 const float* __restrict__ W2, const float* __restrict__ W3,
                 unsigned short* __restrict__ T0, unsigned short* __restrict__ T1,
                 unsigned short* __restrict__ T2, unsigned short* __restrict__ T3)
{
    __shared__ unsigned short Ts[64][65];
    const int b = blockIdx.x, t = threadIdx.x;
    const int mat = b >> 4, tile = b & 15;
    const int r0 = (tile >> 2) * 64, c0 = (tile & 3) * 64;
    const float* W = (mat == 0) ? W0 : (mat == 1) ? W1 : (mat == 2) ? W2 : W3;
    unsigned short* T = (mat == 0) ? T0 : (mat == 1) ? T1 : (mat == 2) ? T2 : T3;
    {
        int r = t >> 2, c4 = (t & 3) * 16;
        #pragma unroll
        for (int j = 0; j < 4; ++j) {
            float4 v = *reinterpret_cast<const float4*>(W + (size_t)(r0 + r) * DIM + c0 + c4 + j * 4);
            Ts[c4 + j * 4 + 0][r] = f2bf(v.x);
            Ts[c4 + j * 4 + 1][r] = f2bf(v.y);
            Ts[c4 + j * 4 + 2][r] = f2bf(v.z);
            Ts[c4 + j * 4 + 3][r] = f2bf(v.w);
        }
    }
    __syncthreads();
    {
        int d = t >> 2, k4 = (t & 3) * 16;
        #pragma unroll
        for (int j = 0; j < 4; ++j) {
            ushort4 u;
            u.x = Ts[d][k4 + j * 4 + 0];
            u.y = Ts[d][k4 + j * 4 + 1];
            u.z = Ts[d][k4 + j * 4 + 2];
            u.w = Ts[d][k4 + j * 4 + 3];
            *reinterpret_cast<ushort4*>(T + (size_t)(c0 + d) * DIM + r0 + k4 + j * 4) = u;
        }
    }
}

// ---------------------------------------------------------------------------
// qkv_mask: blocks [0,384) = QKV projections (MFMA, f32 x input, inline cvt);
// blocks [384,2432) = adj -> bitmask.
// mask layout NATURAL: word[row*64 + wi], bit j = adj[row][wi*64 + j]
// K stored PRE-SCALED by log2(e)/8 so attn's p = exp2(score) directly.
// V token rows permuted within each 64-block: kv -> pos =
//   ((nt&1)<<5)|(lg<<3)|((nt>>1)<<2)|r  (aligns V rows with lane-local P).
// ---------------------------------------------------------------------------
__global__ __launch_bounds__(256)
void qkv_mask(const float* __restrict__ x,
              const unsigned short* __restrict__ WqT, const unsigned short* __restrict__ WkT,
              const unsigned short* __restrict__ WvT,
              const float* __restrict__ bq, const float* __restrict__ bk, const float* __restrict__ bv,
              unsigned short* __restrict__ Qo, unsigned short* __restrict__ Ko,
              unsigned short* __restrict__ VTo,
              const int* __restrict__ adj, unsigned long long* __restrict__ maskT)
{
    const int b = blockIdx.x, t = threadIdx.x, w = t >> 6, l = t & 63;

    if (b >= 384) {
        const int ww = (b - 384) * 4 + w;
        for (int idx = ww; idx < 65536; idx += 8192) {   // idx = row*16 + stripe
            const int row = idx >> 4, st = idx & 15;
            const int* ap = adj + (size_t)row * NN + st * 256 + l;
            const int a0 = ap[0];
            const int a1 = ap[64];
            const int a2 = ap[128];
            const int a3 = ap[192];
            unsigned long long b0 = __ballot(a0 != 0);
            unsigned long long b1 = __ballot(a1 != 0);
            unsigned long long b2 = __ballot(a2 != 0);
            unsigned long long b3 = __ballot(a3 != 0);
            if (l < 4) {
                unsigned long long bb = (l == 0) ? b0 : (l == 1) ? b1 : (l == 2) ? b2 : b3;
                maskT[(size_t)row * 64 + st * 4 + l] = bb;
            }
        }
        return;
    }

    const int l15 = l & 15, lg = l >> 4;
    const int which = b >> 7, xb = b & 127;
    const int row0 = xb * 32 + (w >> 1) * 16;
    const int col0 = (w & 1) * 128;
    const unsigned short* WT; const float* bias;
    if (which == 0)      { WT = WqT; bias = bq; }
    else if (which == 1) { WT = WkT; bias = bk; }
    else                 { WT = WvT; bias = bv; }

    f32x4 acc[8] = {};
    for (int k0 = 0; k0 < DIM; k0 += 32) {
        const float* xp = x + (size_t)(row0 + l15) * DIM + k0 + lg * 8;
        float4 x0 = *reinterpret_cast<const float4*>(xp);
        float4 x1 = *reinterpret_cast<const float4*>(xp + 4);
        union { unsigned u[4]; bf16x8 v; } xa;
        asm("v_cvt_pk_bf16_f32 %0, %1, %2" : "=v"(xa.u[0]) : "v"(x0.x), "v"(x0.y));
        asm("v_cvt_pk_bf16_f32 %0, %1, %2" : "=v"(xa.u[1]) : "v"(x0.z), "v"(x0.w));
        asm("v_cvt_pk_bf16_f32 %0, %1, %2" : "=v"(xa.u[2]) : "v"(x1.x), "v"(x1.y));
        asm("v_cvt_pk_bf16_f32 %0, %1, %2" : "=v"(xa.u[3]) : "v"(x1.z), "v"(x1.w));
        #pragma unroll
        for (int nt = 0; nt < 8; ++nt) {
            bf16x8 wb = *(const bf16x8*)(WT + (size_t)(col0 + nt * 16 + l15) * DIM + k0 + lg * 8);
            acc[nt] = __builtin_amdgcn_mfma_f32_16x16x32_bf16(xa.v, wb, acc[nt], 0, 0, 0);
        }
    }
    #pragma unroll
    for (int nt = 0; nt < 8; ++nt) {
        int col = col0 + nt * 16 + l15;
        float bb = bias[col];
        #pragma unroll
        for (int r = 0; r < 4; ++r) {
            int row = row0 + lg * 4 + r;
            float ov = acc[nt][r] + bb;
            if (which == 1) ov *= 0.18033688f;   // log2(e)/8 folded into K
            unsigned short val = f2bf(ov);
            if (which == 2) {
                int rb = row & 63;
                int vnt = rb >> 4, vlg = (rb >> 2) & 3, vr = rb & 3;
                int pos = ((vnt & 1) << 5) | (vlg << 3) | ((vnt >> 1) << 2) | vr;
                VTo[(size_t)col * NN + ((row & ~63) | pos)] = val;
            } else if (which == 0) Qo[(size_t)row * DIM + col] = val;
            else                   Ko[(size_t)row * DIM + col] = val;
        }
    }
}

// ---------------------------------------------------------------------------
// MFMA flash attention. Block = 128 q; 8 THIN waves x 16 q (512 threads).
// Per-wave structure identical to the proven 52us kernel (VGPR ~52); only
// the block is wider so 8 waves share each 64x64 K/V LDS tile (2x reuse)
// and residency rises: LDS 32KB -> 5 blocks/CU cap, wave cap 32/CU binds
// at 4 blocks x 8 waves. launch_bounds(512,4) keeps the VGPR bound
// non-binding (cap 128) -- R9's spill came from the (512,8) 64-cap.
// Staging: wave w stages K rows [w*8,w*8+8) + V rows [w*8,w*8+8), one
// async16 each, XOR-swizzled source, linear LDS dest. One barrier/tile,
// depth-1 issue-early prefetch. Swapped QK^T (P lane-local, q=l15); V
// pre-permuted so PV A-frag is register packing. K pre-scaled ->
// p = exp2(score). lsum via ones-column MFMA. Grid = 32qb x slices,
// slice-major XCD swizzle (bid&7 = slice&7).
// ---------------------------------------------------------------------------
template<int NTILES>
__global__ __launch_bounds__(512, 4)
void attn_mfma(const unsigned short* __restrict__ Qb, const unsigned short* __restrict__ Kb,
               const unsigned short* __restrict__ VT, const unsigned long long* __restrict__ maskT,
               unsigned short* __restrict__ Opart, float* __restrict__ lpart)
{
    constexpr int NSTR = NTILES / 4;
    __shared__ unsigned short Kt[2][64][64];
    __shared__ unsigned short Vt[2][64][64];

    const int t = threadIdx.x, w = t >> 6, l = t & 63, l15 = l & 15, lg = l >> 4;
    const int bid = blockIdx.x;
    // bid = (slice&7) | (qb<<3) | ((slice>>3)<<8); qb in [0,32)
    const int slice = (bid & 7) + 8 * (bid >> 8);
    const int qb    = (bid >> 3) & 31;
    const int h  = slice & 3;
    const int sp = slice >> 2;
    const int kv_base = sp * NTILES * 64;
    const int qrow = qb * 128 + w * 16;

    const unsigned short* qp = Qb + (size_t)(qrow + l15) * DIM + h * HDIM + lg * 8;
    const bf16x8 qa0 = *(const bf16x8*)(qp);
    const bf16x8 qa1 = *(const bf16x8*)(qp + 32);

    const unsigned long long* mbase = maskT + (size_t)(qrow + l15) * 64 + (kv_base >> 6);

    // staging: wave w covers rows [w*8, w*8+8) of K and of V (1 async16 each)
    const int srow  = w * 8 + (l >> 3);
    const int sunit = (l & 7) ^ (srow & 7);
    const unsigned short* kS = Kb + (size_t)(kv_base + srow) * DIM + h * HDIM + sunit * 8;
    const unsigned short* vS = VT + (size_t)(h * HDIM + srow) * NN + kv_base + sunit * 8;

    const int xr  = l15 & 7;
    const int ko0 = (lg ^ xr) << 4;
    const int ko1 = ((4 + lg) ^ xr) << 4;

    const short onev = (l15 == 0) ? (short)0x3F80 : (short)0;  // bf16 1.0, col 0
    const bf16x8 onesb = {onev, onev, onev, onev, onev, onev, onev, onev};

    f32x4 oa[4] = {};
    f32x4 os = {};

    {   // prologue: stage tile 0 -> buf 0
        async16(kS, &Kt[0][w * 8][0]);
        async16(vS, &Vt[0][w * 8][0]);
    }

    #pragma unroll 1
    for (int st = 0; st < NSTR; ++st) {
        const ulonglong4 m4 = *reinterpret_cast<const ulonglong4*>(mbase + st * 4);

        #pragma unroll
        for (int m = 0; m < 4; ++m) {
            const int tl = st * 4 + m;
            asm volatile("s_waitcnt vmcnt(0)" ::: "memory");   // this tile landed
            __builtin_amdgcn_s_barrier();
            __builtin_amdgcn_sched_barrier(0);

            if (tl + 1 < NTILES) {   // issue next tile into the other buffer
                const int bb = (tl + 1) & 1;
                async16(kS + (size_t)(tl + 1) * 64 * DIM, &Kt[bb][w * 8][0]);
                async16(vS + (tl + 1) * 64,               &Vt[bb][w * 8][0]);
            }

            const int cb = tl & 1;
            const char* kbase = (const char*)&Kt[cb][0][0] + l15 * 128;
            const char* vbase = (const char*)&Vt[cb][0][0] + l15 * 128;

            // QK^T swapped: sa[nt][r] = score[q=l15][kv = nt*16 + lg*4 + r]
            f32x4 sa[4] = {};
            __builtin_amdgcn_s_setprio(1);
            #pragma unroll
            for (int nt = 0; nt < 4; ++nt) {
                bf16x8 kb0 = *(const bf16x8*)(kbase + nt * 2048 + ko0);
                bf16x8 kb1 = *(const bf16x8*)(kbase + nt * 2048 + ko1);
                sa[nt] = __builtin_amdgcn_mfma_f32_16x16x32_bf16(kb0, qa0, sa[nt], 0, 0, 0);
                sa[nt] = __builtin_amdgcn_mfma_f32_16x16x32_bf16(kb1, qa1, sa[nt], 0, 0, 0);
            }
            __builtin_amdgcn_s_setprio(0);

            // masked p = exp2(score); natural mask word, lane shift lg*4
            const unsigned long long w64 =
                (m == 0) ? m4.x : (m == 1) ? m4.y : (m == 2) ? m4.z : m4.w;
            const unsigned long long sh = w64 >> (lg * 4);
            const unsigned shlo = (unsigned)sh, shhi = (unsigned)(sh >> 32);
            float p[4][4];
            #pragma unroll
            for (int nt = 0; nt < 4; ++nt) {
                #pragma unroll
                for (int r = 0; r < 4; ++r) {
                    const int bitpos = nt * 16 + r;
                    const unsigned word = (bitpos < 32) ? shlo : shhi;
                    const unsigned bit = (word >> (bitpos & 31)) & 1u;
                    p[nt][r] = exp2f(bit ? sa[nt][r] : -INFINITY);
                }
            }
            union { unsigned u[4]; bf16x8 v; } a0, a1;
            asm("v_cvt_pk_bf16_f32 %0, %1, %2" : "=v"(a0.u[0]) : "v"(p[0][0]), "v"(p[0][1]));
            asm("v_cvt_pk_bf16_f32 %0, %1, %2" : "=v"(a0.u[1]) : "v"(p[0][2]), "v"(p[0][3]));
            asm("v_cvt_pk_bf16_f32 %0, %1, %2" : "=v"(a0.u[2]) : "v"(p[2][0]), "v"(p[2][1]));
            asm("v_cvt_pk_bf16_f32 %0, %1, %2" : "=v"(a0.u[3]) : "v"(p[2][2]), "v"(p[2][3]));
            asm("v_cvt_pk_bf16_f32 %0, %1, %2" : "=v"(a1.u[0]) : "v"(p[1][0]), "v"(p[1][1]));
            asm("v_cvt_pk_bf16_f32 %0, %1, %2" : "=v"(a1.u[1]) : "v"(p[1][2]), "v"(p[1][3]));
            asm("v_cvt_pk_bf16_f32 %0, %1, %2" : "=v"(a1.u[2]) : "v"(p[3][0]), "v"(p[3][1]));
            asm("v_cvt_pk_bf16_f32 %0, %1, %2" : "=v"(a1.u[3]) : "v"(p[3][2]), "v"(p[3][3]));
            const bf16x8 pa0 = a0.v;
            const bf16x8 pa1 = a1.v;

            // PV + row-sum via ones column (V rows already in fragment order)
            __builtin_amdgcn_s_setprio(1);
            #pragma unroll
            for (int nt = 0; nt < 4; ++nt) {
                bf16x8 vb0 = *(const bf16x8*)(vbase + nt * 2048 + ko0);
                bf16x8 vb1 = *(const bf16x8*)(vbase + nt * 2048 + ko1);
                oa[nt] = __builtin_amdgcn_mfma_f32_16x16x32_bf16(pa0, vb0, oa[nt], 0, 0, 0);
                oa[nt] = __builtin_amdgcn_mfma_f32_16x16x32_bf16(pa1, vb1, oa[nt], 0, 0, 0);
            }
            os = __builtin_amdgcn_mfma_f32_16x16x32_bf16(pa0, onesb, os, 0, 0, 0);
            os = __builtin_amdgcn_mfma_f32_16x16x32_bf16(pa1, onesb, os, 0, 0, 0);
            __builtin_amdgcn_s_setprio(0);
            // no exit barrier: next tile's entry barrier + buffer parity protect
        }
    }

    #pragma unroll
    for (int r = 0; r < 4; ++r) {
        const int qr = qrow + lg * 4 + r;
        #pragma unroll
        for (int nt = 0; nt < 4; ++nt)
            Opart[((size_t)sp * NN + qr) * DIM + h * HDIM + nt * 16 + l15] = f2bf(oa[nt][r]);
        if (l15 == 0)
            lpart[((size_t)sp * NN + qr) * NHEADS + h] = os[r];
    }
}

// ---------------------------------------------------------------------------
// out_ln_fused: combine kv-splits (normalize) into LDS, then output
// projection + bias + residual + LayerNorm. 256 blocks x 16 rows.
// ---------------------------------------------------------------------------
__global__ __launch_bounds__(256)
void out_ln_fused(const unsigned short* __restrict__ Opart, const float* __restrict__ lpart,
                  const unsigned short* __restrict__ WoT, const float* __restrict__ bo,
                  const unsigned short* __restrict__ Rb, const float* __restrict__ gamma,
                  const float* __restrict__ beta, float* __restrict__ out, int S)
{
    __shared__ unsigned short As[16][264];
    __shared__ float redsum[4][16];
    __shared__ float redsq[4][16];
    const int t = threadIdx.x, w = t >> 6, l = t & 63, l15 = l & 15, lg = l >> 4;
    const int row0 = blockIdx.x * 16;

    {   // combine: thread -> row = t>>4 (16), d-chunk = (t&15)*16
        const int row = t >> 4;
        const int d0  = (t & 15) * 16;
        const int hh  = d0 >> 6;
        float lsum = 0.f;
        for (int s = 0; s < S; ++s)
            lsum += lpart[((size_t)s * NN + row0 + row) * NHEADS + hh];
        const float inv = 1.f / lsum;
        float a16[16] = {};
        for (int s = 0; s < S; ++s) {
            const unsigned short* op = Opart + ((size_t)s * NN + row0 + row) * DIM + d0;
            #pragma unroll
            for (int j4 = 0; j4 < 4; ++j4) {
                ushort4 u = *reinterpret_cast<const ushort4*>(op + j4 * 4);
                a16[j4 * 4 + 0] += bf2f(u.x);
                a16[j4 * 4 + 1] += bf2f(u.y);
                a16[j4 * 4 + 2] += bf2f(u.z);
                a16[j4 * 4 + 3] += bf2f(u.w);
            }
        }
        #pragma unroll
        for (int j4 = 0; j4 < 4; ++j4) {
            ushort4 ov;
            ov.x = f2bf(a16[j4 * 4 + 0] * inv);
            ov.y = f2bf(a16[j4 * 4 + 1] * inv);
            ov.z = f2bf(a16[j4 * 4 + 2] * inv);
            ov.w = f2bf(a16[j4 * 4 + 3] * inv);
            *reinterpret_cast<ushort4*>(&As[row][d0 + j4 * 4]) = ov;
        }
    }
    __syncthreads();

    const int col0 = w * 64;
    f32x4 acc[4] = {};
    for (int k0 = 0; k0 < DIM; k0 += 32) {
        bf16x8 xa = *reinterpret_cast<const bf16x8*>(&As[l15][k0 + lg * 8]);
        #pragma unroll
        for (int nt = 0; nt < 4; ++nt) {
            bf16x8 wb = *(const bf16x8*)(WoT + (size_t)(col0 + nt * 16 + l15) * DIM + k0 + lg * 8);
            acc[nt] = __builtin_amdgcn_mfma_f32_16x16x32_bf16(xa, wb, acc[nt], 0, 0, 0);
        }
    }

    float psum[4] = {0, 0, 0, 0}, psq[4] = {0, 0, 0, 0};
    #pragma unroll
    for (int nt = 0; nt < 4; ++nt) {
        int col = col0 + nt * 16 + l15;
        float bb = bo[col];
        #pragma unroll
        for (int r = 0; r < 4; ++r) {
            int row = row0 + lg * 4 + r;
            float xv = acc[nt][r] + bb + bf2f(Rb[(size_t)row * DIM + col]);
            acc[nt][r] = xv;
            psum[r] += xv; psq[r] += xv * xv;
        }
    }
    #pragma unroll
    for (int r = 0; r < 4; ++r) {
        float s = psum[r], q = psq[r];
        s += __shfl_xor(s, 1); q += __shfl_xor(q, 1);
        s += __shfl_xor(s, 2); q += __shfl_xor(q, 2);
        s += __shfl_xor(s, 4); q += __shfl_xor(q, 4);
        s += __shfl_xor(s, 8); q += __shfl_xor(q, 8);
        psum[r] = s; psq[r] = q;
    }
    if (l15 == 0) {
        #pragma unroll
        for (int r = 0; r < 4; ++r) {
            redsum[w][lg * 4 + r] = psum[r];
            redsq[w][lg * 4 + r]  = psq[r];
        }
    }
    __syncthreads();

    float msave[4], rsave[4];
    #pragma unroll
    for (int r = 0; r < 4; ++r) {
        int row = lg * 4 + r;
        float s = redsum[0][row] + redsum[1][row] + redsum[2][row] + redsum[3][row];
        float q = redsq[0][row] + redsq[1][row] + redsq[2][row] + redsq[3][row];
        float mean = s * (1.f / 256.f);
        float var  = q * (1.f / 256.f) - mean * mean;
        msave[r] = mean;
        rsave[r] = rsqrtf(var + 1e-5f);
    }
    #pragma unroll
    for (int nt = 0; nt < 4; ++nt) {
        int col = col0 + nt * 16 + l15;
        float g = gamma[col], bt = beta[col];
        #pragma unroll
        for (int r = 0; r < 4; ++r) {
            int row = row0 + lg * 4 + r;
            out[(size_t)row * DIM + col] = (acc[nt][r] - msave[r]) * rsave[r] * g + bt;
        }
    }
}

// ---------------------------------------------------------------------------
extern "C" void kernel_launch(void* const* d_in, const int* in_sizes, int n_in,
                              void* d_out, int out_size, void* d_ws, size_t ws_size,
                              hipStream_t stream) {
    const float* x     = (const float*)d_in[0];
    const int*   adj   = (const int*)  d_in[1];
    const float* Wq    = (const float*)d_in[2];
    const float* bq    = (const float*)d_in[3];
    const float* Wk    = (const float*)d_in[4];
    const float* bk    = (const float*)d_in[5];
    const float* Wv    = (const float*)d_in[6];
    const float* bv    = (const float*)d_in[7];
    const float* Wo    = (const float*)d_in[8];
    const float* bo    = (const float*)d_in[9];
    const float* gamma = (const float*)d_in[10];
    const float* beta  = (const float*)d_in[11];
    float* out = (float*)d_out;

    char* ws = (char*)d_ws;
    const size_t MB = 1u << 20;
    unsigned short*     Qb    = (unsigned short*)(ws + 0 * MB);        // 2 MB
    unsigned short*     Kb    = (unsigned short*)(ws + 2 * MB);        // 2 MB
    unsigned short*     VT    = (unsigned short*)(ws + 4 * MB);        // 2 MB
    unsigned long long* maskT = (unsigned long long*)(ws + 6 * MB);    // 2 MB
    unsigned short*     WqT   = (unsigned short*)(ws + 8 * MB);        // 4 x 128 KB
    unsigned short*     WkT   = (unsigned short*)(ws + 8 * MB + 128 * 1024);
    unsigned short*     WvT   = (unsigned short*)(ws + 8 * MB + 256 * 1024);
    unsigned short*     WoT   = (unsigned short*)(ws + 8 * MB + 384 * 1024);
    float*              lpart = (float*)(ws + 10 * MB + 512 * 1024);   // 512 KB
    unsigned short*     Opart = (unsigned short*)(ws + 11 * MB);       // 16 MB (S=8)

    const int S = (ws_size >= 27 * MB) ? 8 : 4;

    prep_kernel<<<64, 256, 0, stream>>>(Wq, Wk, Wv, Wo, WqT, WkT, WvT, WoT);

    qkv_mask<<<384 + 2048, 256, 0, stream>>>(
        x, WqT, WkT, WvT, bq, bk, bv, Qb, Kb, VT, adj, maskT);

    if (S == 8)
        attn_mfma<8><<<1024, 512, 0, stream>>>(Qb, Kb, VT, maskT, Opart, lpart);
    else
        attn_mfma<16><<<512, 512, 0, stream>>>(Qb, Kb, VT, maskT, Opart, lpart);

    out_ln_fused<<<NN / 16, 256, 0, stream>>>(
        Opart, lpart, WoT, bo, Qb, gamma, beta, out, S);
}